// Round 7
// baseline (796.882 us; speedup 1.0000x reference)
//
#include <hip/hip_runtime.h>
#include <hip/hip_cooperative_groups.h>
#include <hip/hip_bf16.h>
#include <stdint.h>

namespace cg = cooperative_groups;

// Problem constants
#define BATCH 64
#define IN_CAPS 512          // In (input capsules)
#define NCAP 16              // num_capsule
#define DCAP 64              // dim_capsule
#define GN (NCAP * DCAP)     // 1024
#define GM (BATCH * IN_CAPS) // 32768
#define GK 768               // input feature dim (K)

typedef __bf16 bf16;
typedef __attribute__((ext_vector_type(8))) __bf16 bf16x8;
typedef __attribute__((ext_vector_type(4))) __bf16 bf16x4;
typedef __attribute__((ext_vector_type(4))) float f32x4;

// async global->LDS 16B copy (wave-uniform LDS base + lane*16)
__device__ inline void async16(const bf16* g, bf16* l) {
    __builtin_amdgcn_global_load_lds(
        (__attribute__((address_space(1))) void*)g,
        (__attribute__((address_space(3))) void*)l, 16, 0, 0);
}

// ---------------------------------------------------------------------------
// Kernel 1: X (fp32) -> bf16, pure-BW pre-convert for global_load_lds staging.
// ---------------------------------------------------------------------------
__global__ __launch_bounds__(256) void k_convX(const float* __restrict__ X,
                                               bf16* __restrict__ Xb) {
    const size_t i = ((size_t)blockIdx.x * 256 + threadIdx.x) * 8;
    const f32x4 a = *(const f32x4*)(X + i);
    const f32x4 b = *(const f32x4*)(X + i + 4);
    bf16x8 r;
    r[0] = (bf16)a[0]; r[1] = (bf16)a[1]; r[2] = (bf16)a[2]; r[3] = (bf16)a[3];
    r[4] = (bf16)b[0]; r[5] = (bf16)b[1]; r[6] = (bf16)b[2]; r[7] = (bf16)b[3];
    *(bf16x8*)(Xb + i) = r;
}

// ---------------------------------------------------------------------------
// Kernel 2: transpose W [768][1024] fp32 -> Wt [1024][768] bf16 (K-contig).
// ---------------------------------------------------------------------------
__global__ void k_transW(const float* __restrict__ W, bf16* __restrict__ Wt) {
    __shared__ bf16 t[32][33];
    const int k0 = blockIdx.x * 32;
    const int n0 = blockIdx.y * 32;
    const int tx = threadIdx.x, ty = threadIdx.y;
#pragma unroll
    for (int r = 0; r < 4; ++r)
        t[ty + r * 8][tx] = (bf16)W[(size_t)(k0 + ty + r * 8) * GN + n0 + tx];
    __syncthreads();
#pragma unroll
    for (int r = 0; r < 4; ++r)
        Wt[(size_t)(n0 + ty + r * 8) * GK + k0 + tx] = t[tx][ty + r * 8];
}

// ---------------------------------------------------------------------------
// Kernel 3a: MFMA GEMM, async global->LDS staging (validated; frozen).
//   U: [b][cap][j][k] bf16  (b=m>>9, j=m&511, cap=n>>6, k=n&63)
// ---------------------------------------------------------------------------
__global__ __launch_bounds__(256) void k_gemm_async(const bf16* __restrict__ Xb,
                                                    const bf16* __restrict__ Wt,
                                                    bf16* __restrict__ U) {
    __shared__ bf16 sA[128 * 32];
    __shared__ bf16 sB[128 * 32];

    const int tid = threadIdx.x;
    const int lane = tid & 63;
    const int wave = tid >> 6;
    const int wm = wave >> 1, wn = wave & 1;
    const int m0 = blockIdx.x * 128;
    const int n0 = blockIdx.y * 128;

    const int c0 = wave * 2, c1 = wave * 2 + 1;
    const int rl = lane >> 2, cl = (lane & 3) * 8;
    const bf16* gA0 = Xb + (size_t)(m0 + c0 * 16 + rl) * GK + cl;
    const bf16* gA1 = Xb + (size_t)(m0 + c1 * 16 + rl) * GK + cl;
    const bf16* gB0 = Wt + (size_t)(n0 + c0 * 16 + rl) * GK + cl;
    const bf16* gB1 = Wt + (size_t)(n0 + c1 * 16 + rl) * GK + cl;
    bf16* lA0 = sA + c0 * 512;
    bf16* lA1 = sA + c1 * 512;
    bf16* lB0 = sB + c0 * 512;
    bf16* lB1 = sB + c1 * 512;

    f32x4 acc[4][4] = {};
    const int fr = lane & 15;
    const int fq = lane >> 4;

    for (int kt = 0; kt < GK / 32; ++kt) {
        __syncthreads();
        async16(gA0, lA0);
        async16(gA1, lA1);
        async16(gB0, lB0);
        async16(gB1, lB1);
        gA0 += 32; gA1 += 32; gB0 += 32; gB1 += 32;
        __syncthreads();

        bf16x8 af[4], bfr[4];
#pragma unroll
        for (int mi = 0; mi < 4; ++mi)
            af[mi] = *(const bf16x8*)(sA + (wm * 64 + mi * 16 + fr) * 32 + fq * 8);
#pragma unroll
        for (int ni = 0; ni < 4; ++ni)
            bfr[ni] = *(const bf16x8*)(sB + (wn * 64 + ni * 16 + fr) * 32 + fq * 8);
#pragma unroll
        for (int mi = 0; mi < 4; ++mi)
#pragma unroll
            for (int ni = 0; ni < 4; ++ni)
                acc[mi][ni] = __builtin_amdgcn_mfma_f32_16x16x32_bf16(
                    af[mi], bfr[ni], acc[mi][ni], 0, 0, 0);
    }

#pragma unroll
    for (int mi = 0; mi < 4; ++mi) {
#pragma unroll
        for (int ni = 0; ni < 4; ++ni) {
#pragma unroll
            for (int r = 0; r < 4; ++r) {
                const int m = m0 + wm * 64 + mi * 16 + fq * 4 + r;
                const int n = n0 + wn * 64 + ni * 16 + fr;
                const int bb = m >> 9, j = m & 511;
                const int ci = n >> 6, k = n & 63;
                U[(((size_t)(bb * NCAP + ci)) * IN_CAPS + j) * DCAP + k] =
                    (bf16)acc[mi][ni][r];
            }
        }
    }
}

// ---------------------------------------------------------------------------
// Kernel 3b: fallback GEMM (validated round-4 structure, inline conversion).
// ---------------------------------------------------------------------------
__global__ __launch_bounds__(256) void k_gemm_inline(const float* __restrict__ X,
                                                     const bf16* __restrict__ Wt,
                                                     bf16* __restrict__ U) {
    __shared__ bf16 sA[128 * 32];
    __shared__ bf16 sB[128 * 32];
    const int tid = threadIdx.x;
    const int lane = tid & 63;
    const int wave = tid >> 6;
    const int wm = wave >> 1, wn = wave & 1;
    const int m0 = blockIdx.x * 128;
    const int n0 = blockIdx.y * 128;
    const int srow = tid >> 2;
    const int scol = (tid & 3) * 8;
    f32x4 acc[4][4] = {};
    const int fr = lane & 15;
    const int fq = lane >> 4;
    for (int kt = 0; kt < GK / 32; ++kt) {
        const int kb = kt * 32;
        bf16x8 a0, a1, b0, b1;
        {
            const float* p = X + (size_t)(m0 + srow) * GK + kb + scol;
            const f32x4 x0 = *(const f32x4*)p, x1 = *(const f32x4*)(p + 4);
            const float* q = X + (size_t)(m0 + srow + 64) * GK + kb + scol;
            const f32x4 y0 = *(const f32x4*)q, y1 = *(const f32x4*)(q + 4);
#pragma unroll
            for (int c = 0; c < 4; ++c) {
                a0[c] = (bf16)x0[c]; a0[c + 4] = (bf16)x1[c];
                a1[c] = (bf16)y0[c]; a1[c + 4] = (bf16)y1[c];
            }
        }
        b0 = *(const bf16x8*)(Wt + (size_t)(n0 + srow) * GK + kb + scol);
        b1 = *(const bf16x8*)(Wt + (size_t)(n0 + srow + 64) * GK + kb + scol);
        __syncthreads();
        *(bf16x8*)(sA + srow * 32 + scol) = a0;
        *(bf16x8*)(sA + (srow + 64) * 32 + scol) = a1;
        *(bf16x8*)(sB + srow * 32 + scol) = b0;
        *(bf16x8*)(sB + (srow + 64) * 32 + scol) = b1;
        __syncthreads();
        bf16x8 af[4], bfr[4];
#pragma unroll
        for (int mi = 0; mi < 4; ++mi)
            af[mi] = *(const bf16x8*)(sA + (wm * 64 + mi * 16 + fr) * 32 + fq * 8);
#pragma unroll
        for (int ni = 0; ni < 4; ++ni)
            bfr[ni] = *(const bf16x8*)(sB + (wn * 64 + ni * 16 + fr) * 32 + fq * 8);
#pragma unroll
        for (int mi = 0; mi < 4; ++mi)
#pragma unroll
            for (int ni = 0; ni < 4; ++ni)
                acc[mi][ni] = __builtin_amdgcn_mfma_f32_16x16x32_bf16(
                    af[mi], bfr[ni], acc[mi][ni], 0, 0, 0);
    }
#pragma unroll
    for (int mi = 0; mi < 4; ++mi) {
#pragma unroll
        for (int ni = 0; ni < 4; ++ni) {
#pragma unroll
            for (int r = 0; r < 4; ++r) {
                const int m = m0 + wm * 64 + mi * 16 + fq * 4 + r;
                const int n = n0 + wn * 64 + ni * 16 + fr;
                const int bb = m >> 9, j = m & 511;
                const int ci = n >> 6, k = n & 63;
                U[(((size_t)(bb * NCAP + ci)) * IN_CAPS + j) * DCAP + k] =
                    (bf16)acc[mi][ni][r];
            }
        }
    }
}

// ---------------------------------------------------------------------------
// Kernel 4a: COOPERATIVE fused routing — all 3 iterations in one kernel.
// Block = (b,cap); the 64-KiB U slice lives in 64 VGPRs (16 x bf16x8/thread)
// for the whole kernel: U is read from HBM exactly ONCE. Cross-capsule
// softmax coupling handled by grid.sync() between logit-write and
// softmax-read (+ __threadfence for cross-XCD visibility).
// Thread t: k-octet g=t&7 (k=g*8..g*8+7), j-group jr=t>>3 (j=it*32+jr).
// ---------------------------------------------------------------------------
__global__ __launch_bounds__(256, 4) void k_route_coop(const bf16* __restrict__ U,
                                                       float* __restrict__ BL,
                                                       float* __restrict__ OutC) {
    __shared__ float sc[IN_CAPS];  // 2 KiB
    __shared__ float red[32][64];  // 8 KiB
    __shared__ float sout[64];     // 256 B
    const int bi = blockIdx.x;
    const int b = bi >> 4, cap = bi & 15;
    const int tid = threadIdx.x;
    const int g = tid & 7, jr = tid >> 3;
    const size_t ubase = (size_t)bi * IN_CAPS * DCAP;

    // U slice -> registers (once)
    bf16x8 v[16];
#pragma unroll
    for (int it = 0; it < 16; ++it)
        v[it] = *(const bf16x8*)(U + ubase + (size_t)it * 2048 + tid * 8);

    for (int iter = 0; iter < 3; ++iter) {
        // --- c coefficients: softmax over the 16-capsule axis (iter>0) ---
        if (iter > 0) {
#pragma unroll
            for (int h = 0; h < 2; ++h) {
                const int j = tid + h * 256;
                const float* p = BL + (size_t)b * NCAP * IN_CAPS + j;
                float vv[16], mx = -1e30f;
#pragma unroll
                for (int i = 0; i < 16; ++i) {
                    vv[i] = p[(size_t)i * IN_CAPS];
                    mx = fmaxf(mx, vv[i]);
                }
                float s = 0.f;
#pragma unroll
                for (int i = 0; i < 16; ++i) s += __expf(vv[i] - mx);
                sc[j] = __expf(vv[cap] - mx) / s;
            }
            __syncthreads();
        }

        // --- phase A: weighted sum over j (from registers) ---
        float acc[8] = {};
#pragma unroll
        for (int it = 0; it < 16; ++it) {
            const float cv = (iter == 0) ? 0.0625f : sc[it * 32 + jr];
#pragma unroll
            for (int c = 0; c < 8; ++c) acc[c] += cv * (float)v[it][c];
        }
        *(f32x4*)(&red[jr][g * 8]) = f32x4{acc[0], acc[1], acc[2], acc[3]};
        *(f32x4*)(&red[jr][g * 8 + 4]) = f32x4{acc[4], acc[5], acc[6], acc[7]};
        __syncthreads();

        // --- reduce + squash ---
        if (tid < 64) {
            float s = 0.f;
#pragma unroll
            for (int r = 0; r < 32; ++r) s += red[r][tid];
            float ss = s * s;
#pragma unroll
            for (int off = 32; off >= 1; off >>= 1) ss += __shfl_xor(ss, off);
            const float val = s * rsqrtf(ss + 1e-7f);
            sout[tid] = val;
            if (iter == 2) OutC[(size_t)bi * DCAP + tid] = val;
        }
        if (iter == 2) return; // block-uniform
        __syncthreads();

        // --- phase B: logits from registers ---
        const f32x4 o0 = *(const f32x4*)(sout + g * 8);
        const f32x4 o1 = *(const f32x4*)(sout + g * 8 + 4);
#pragma unroll
        for (int it = 0; it < 16; ++it) {
            float p = o0[0] * (float)v[it][0] + o0[1] * (float)v[it][1] +
                      o0[2] * (float)v[it][2] + o0[3] * (float)v[it][3] +
                      o1[0] * (float)v[it][4] + o1[1] * (float)v[it][5] +
                      o1[2] * (float)v[it][6] + o1[3] * (float)v[it][7];
            p += __shfl_xor(p, 1);
            p += __shfl_xor(p, 2);
            p += __shfl_xor(p, 4);
            if (g == 0) BL[((size_t)b * NCAP + cap) * IN_CAPS + it * 32 + jr] = p;
        }
        __threadfence(); // device-scope: BL visible across XCDs
        cg::this_grid().sync();
        __syncthreads(); // sc/red reuse safety
    }
}

// ---------------------------------------------------------------------------
// Kernel 4b: fallback routing pass (round-6 validated) if cooperative launch
// is unavailable. mode 0: c=1/16; 1: softmax(BL); 2: final, write OutC.
// ---------------------------------------------------------------------------
__global__ __launch_bounds__(256) void k_route(const bf16* __restrict__ U,
                                               float* __restrict__ BL,
                                               float* __restrict__ OutC,
                                               int mode) {
    __shared__ float sc[IN_CAPS];
    __shared__ float red[32][64];
    __shared__ float sout[64];
    const int bi = blockIdx.x;
    const int b = bi >> 4, cap = bi & 15;
    const int tid = threadIdx.x;
    const size_t ubase = (size_t)bi * IN_CAPS * DCAP;

    if (mode == 0) {
        sc[tid] = 0.0625f;
        sc[tid + 256] = 0.0625f;
    } else {
#pragma unroll
        for (int h = 0; h < 2; ++h) {
            const int j = tid + h * 256;
            const float* p = BL + (size_t)b * NCAP * IN_CAPS + j;
            float v[16], mx = -1e30f;
#pragma unroll
            for (int i = 0; i < 16; ++i) {
                v[i] = p[(size_t)i * IN_CAPS];
                mx = fmaxf(mx, v[i]);
            }
            float s = 0.f;
#pragma unroll
            for (int i = 0; i < 16; ++i) s += __expf(v[i] - mx);
            sc[j] = __expf(v[cap] - mx) / s;
        }
    }
    __syncthreads();

    const int g = tid & 7;
    const int jr = tid >> 3;

    float acc[8] = {};
#pragma unroll
    for (int it = 0; it < 16; ++it) {
        const int j = it * 32 + jr;
        const bf16x8 v = *(const bf16x8*)(U + ubase + (size_t)it * 2048 + tid * 8);
        const float cv = sc[j];
#pragma unroll
        for (int c = 0; c < 8; ++c) acc[c] += cv * (float)v[c];
    }
    *(f32x4*)(&red[jr][g * 8]) = f32x4{acc[0], acc[1], acc[2], acc[3]};
    *(f32x4*)(&red[jr][g * 8 + 4]) = f32x4{acc[4], acc[5], acc[6], acc[7]};
    __syncthreads();

    if (tid < 64) {
        float s = 0.f;
#pragma unroll
        for (int r = 0; r < 32; ++r) s += red[r][tid];
        float ss = s * s;
#pragma unroll
        for (int off = 32; off >= 1; off >>= 1) ss += __shfl_xor(ss, off);
        const float val = s * rsqrtf(ss + 1e-7f);
        sout[tid] = val;
        if (mode == 2) OutC[(size_t)bi * DCAP + tid] = val;
    }
    if (mode == 2) return;
    __syncthreads();

    const f32x4 o0 = *(const f32x4*)(sout + g * 8);
    const f32x4 o1 = *(const f32x4*)(sout + g * 8 + 4);
#pragma unroll
    for (int it = 0; it < 16; ++it) {
        const int j = it * 32 + jr;
        const bf16x8 v = *(const bf16x8*)(U + ubase + (size_t)it * 2048 + tid * 8);
        float p = o0[0] * (float)v[0] + o0[1] * (float)v[1] +
                  o0[2] * (float)v[2] + o0[3] * (float)v[3] +
                  o1[0] * (float)v[4] + o1[1] * (float)v[5] +
                  o1[2] * (float)v[6] + o1[3] * (float)v[7];
        p += __shfl_xor(p, 1);
        p += __shfl_xor(p, 2);
        p += __shfl_xor(p, 4);
        if (g == 0) BL[((size_t)b * NCAP + cap) * IN_CAPS + j] = p;
    }
}

// ---------------------------------------------------------------------------
extern "C" void kernel_launch(void* const* d_in, const int* in_sizes, int n_in,
                              void* d_out, int out_size, void* d_ws, size_t ws_size,
                              hipStream_t stream) {
    const float* X = (const float*)d_in[0]; // [64][512][768] fp32
    const float* W = (const float*)d_in[1]; // [768][1024] fp32
    float* OutC = (float*)d_out;            // [64][16][64] fp32

    const size_t u_bytes = (size_t)BATCH * NCAP * IN_CAPS * DCAP * sizeof(bf16); // 64 MiB
    const size_t xb_bytes = (size_t)GM * GK * sizeof(bf16);                      // 48 MiB
    const size_t wt_bytes = (size_t)GN * GK * sizeof(bf16);                      // 1.5 MiB
    const size_t bl_bytes = (size_t)BATCH * NCAP * IN_CAPS * sizeof(float);      // 2 MiB
    char* ws = (char*)d_ws;

    const size_t need_big = u_bytes + xb_bytes + wt_bytes + bl_bytes;
    const size_t need_small = u_bytes + wt_bytes + bl_bytes;

    bf16* U = (bf16*)ws;
    bf16* Wt;
    float* BL;

    if (ws_size >= need_big) {
        bf16* Xb = (bf16*)(ws + u_bytes);
        Wt = (bf16*)(ws + u_bytes + xb_bytes);
        BL = (float*)(ws + u_bytes + xb_bytes + wt_bytes);
        k_convX<<<GM * GK / (256 * 8), 256, 0, stream>>>(X, Xb);
        k_transW<<<dim3(GK / 32, GN / 32), dim3(32, 8), 0, stream>>>(W, Wt);
        k_gemm_async<<<dim3(GM / 128, GN / 128), 256, 0, stream>>>(Xb, Wt, U);
    } else if (ws_size >= need_small) {
        Wt = (bf16*)(ws + u_bytes);
        BL = (float*)(ws + u_bytes + wt_bytes);
        k_transW<<<dim3(GK / 32, GN / 32), dim3(32, 8), 0, stream>>>(W, Wt);
        k_gemm_inline<<<dim3(GM / 128, GN / 128), 256, 0, stream>>>(X, Wt, U);
    } else {
        return;
    }

    // routing: single cooperative kernel (U register-resident, read once);
    // fall back to the validated 3-pass path if cooperative launch fails.
    const bf16* Uc = U;
    void* args[] = {(void*)&Uc, (void*)&BL, (void*)&OutC};
    hipError_t ce = hipLaunchCooperativeKernel((void*)k_route_coop,
                                               dim3(BATCH * NCAP), dim3(256),
                                               args, 0, stream);
    if (ce != hipSuccess) {
        k_route<<<BATCH * NCAP, 256, 0, stream>>>(U, BL, OutC, 0);
        k_route<<<BATCH * NCAP, 256, 0, stream>>>(U, BL, OutC, 1);
        k_route<<<BATCH * NCAP, 256, 0, stream>>>(U, BL, OutC, 2);
    }
}

// Round 8
// 285.658 us; speedup vs baseline: 2.7896x; 2.7896x over previous
//
#include <hip/hip_runtime.h>
#include <hip/hip_bf16.h>
#include <stdint.h>

// Problem constants
#define BATCH 64
#define IN_CAPS 512          // In (input capsules)
#define NCAP 16              // num_capsule
#define DCAP 64              // dim_capsule
#define GN (NCAP * DCAP)     // 1024
#define GM (BATCH * IN_CAPS) // 32768
#define GK 768               // input feature dim (K)

typedef __bf16 bf16;
typedef __attribute__((ext_vector_type(8))) __bf16 bf16x8;
typedef __attribute__((ext_vector_type(4))) float f32x4;

// async global->LDS 16B copy (wave-uniform LDS base + lane*16)
__device__ inline void async16(const bf16* g, bf16* l) {
    __builtin_amdgcn_global_load_lds(
        (__attribute__((address_space(1))) void*)g,
        (__attribute__((address_space(3))) void*)l, 16, 0, 0);
}

// ---------------------------------------------------------------------------
// Kernel 1: X (fp32) -> bf16, pure-BW pre-convert for global_load_lds staging.
// ---------------------------------------------------------------------------
__global__ __launch_bounds__(256) void k_convX(const float* __restrict__ X,
                                               bf16* __restrict__ Xb) {
    const size_t i = ((size_t)blockIdx.x * 256 + threadIdx.x) * 8;
    const f32x4 a = *(const f32x4*)(X + i);
    const f32x4 b = *(const f32x4*)(X + i + 4);
    bf16x8 r;
    r[0] = (bf16)a[0]; r[1] = (bf16)a[1]; r[2] = (bf16)a[2]; r[3] = (bf16)a[3];
    r[4] = (bf16)b[0]; r[5] = (bf16)b[1]; r[6] = (bf16)b[2]; r[7] = (bf16)b[3];
    *(bf16x8*)(Xb + i) = r;
}

// ---------------------------------------------------------------------------
// Kernel 2: transpose W [768][1024] fp32 -> Wt [1024][768] bf16 (K-contig).
// ---------------------------------------------------------------------------
__global__ void k_transW(const float* __restrict__ W, bf16* __restrict__ Wt) {
    __shared__ bf16 t[32][33];
    const int k0 = blockIdx.x * 32;
    const int n0 = blockIdx.y * 32;
    const int tx = threadIdx.x, ty = threadIdx.y;
#pragma unroll
    for (int r = 0; r < 4; ++r)
        t[ty + r * 8][tx] = (bf16)W[(size_t)(k0 + ty + r * 8) * GN + n0 + tx];
    __syncthreads();
#pragma unroll
    for (int r = 0; r < 4; ++r)
        Wt[(size_t)(n0 + ty + r * 8) * GK + k0 + tx] = t[tx][ty + r * 8];
}

// ---------------------------------------------------------------------------
// Kernel 3a: MFMA GEMM, async global->LDS staging (validated; frozen).
//   U: [b][cap][j][k] bf16  (b=m>>9, j=m&511, cap=n>>6, k=n&63)
// ---------------------------------------------------------------------------
__global__ __launch_bounds__(256) void k_gemm_async(const bf16* __restrict__ Xb,
                                                    const bf16* __restrict__ Wt,
                                                    bf16* __restrict__ U) {
    __shared__ bf16 sA[128 * 32];
    __shared__ bf16 sB[128 * 32];

    const int tid = threadIdx.x;
    const int lane = tid & 63;
    const int wave = tid >> 6;
    const int wm = wave >> 1, wn = wave & 1;
    const int m0 = blockIdx.x * 128;
    const int n0 = blockIdx.y * 128;

    const int c0 = wave * 2, c1 = wave * 2 + 1;
    const int rl = lane >> 2, cl = (lane & 3) * 8;
    const bf16* gA0 = Xb + (size_t)(m0 + c0 * 16 + rl) * GK + cl;
    const bf16* gA1 = Xb + (size_t)(m0 + c1 * 16 + rl) * GK + cl;
    const bf16* gB0 = Wt + (size_t)(n0 + c0 * 16 + rl) * GK + cl;
    const bf16* gB1 = Wt + (size_t)(n0 + c1 * 16 + rl) * GK + cl;
    bf16* lA0 = sA + c0 * 512;
    bf16* lA1 = sA + c1 * 512;
    bf16* lB0 = sB + c0 * 512;
    bf16* lB1 = sB + c1 * 512;

    f32x4 acc[4][4] = {};
    const int fr = lane & 15;
    const int fq = lane >> 4;

    for (int kt = 0; kt < GK / 32; ++kt) {
        __syncthreads();
        async16(gA0, lA0);
        async16(gA1, lA1);
        async16(gB0, lB0);
        async16(gB1, lB1);
        gA0 += 32; gA1 += 32; gB0 += 32; gB1 += 32;
        __syncthreads();

        bf16x8 af[4], bfr[4];
#pragma unroll
        for (int mi = 0; mi < 4; ++mi)
            af[mi] = *(const bf16x8*)(sA + (wm * 64 + mi * 16 + fr) * 32 + fq * 8);
#pragma unroll
        for (int ni = 0; ni < 4; ++ni)
            bfr[ni] = *(const bf16x8*)(sB + (wn * 64 + ni * 16 + fr) * 32 + fq * 8);
#pragma unroll
        for (int mi = 0; mi < 4; ++mi)
#pragma unroll
            for (int ni = 0; ni < 4; ++ni)
                acc[mi][ni] = __builtin_amdgcn_mfma_f32_16x16x32_bf16(
                    af[mi], bfr[ni], acc[mi][ni], 0, 0, 0);
    }

#pragma unroll
    for (int mi = 0; mi < 4; ++mi) {
#pragma unroll
        for (int ni = 0; ni < 4; ++ni) {
#pragma unroll
            for (int r = 0; r < 4; ++r) {
                const int m = m0 + wm * 64 + mi * 16 + fq * 4 + r;
                const int n = n0 + wn * 64 + ni * 16 + fr;
                const int bb = m >> 9, j = m & 511;
                const int ci = n >> 6, k = n & 63;
                U[(((size_t)(bb * NCAP + ci)) * IN_CAPS + j) * DCAP + k] =
                    (bf16)acc[mi][ni][r];
            }
        }
    }
}

// ---------------------------------------------------------------------------
// Kernel 3b: fallback GEMM (validated, inline conversion) — only if ws small.
// ---------------------------------------------------------------------------
__global__ __launch_bounds__(256) void k_gemm_inline(const float* __restrict__ X,
                                                     const bf16* __restrict__ Wt,
                                                     bf16* __restrict__ U) {
    __shared__ bf16 sA[128 * 32];
    __shared__ bf16 sB[128 * 32];
    const int tid = threadIdx.x;
    const int lane = tid & 63;
    const int wave = tid >> 6;
    const int wm = wave >> 1, wn = wave & 1;
    const int m0 = blockIdx.x * 128;
    const int n0 = blockIdx.y * 128;
    const int srow = tid >> 2;
    const int scol = (tid & 3) * 8;
    f32x4 acc[4][4] = {};
    const int fr = lane & 15;
    const int fq = lane >> 4;
    for (int kt = 0; kt < GK / 32; ++kt) {
        const int kb = kt * 32;
        bf16x8 a0, a1, b0, b1;
        {
            const float* p = X + (size_t)(m0 + srow) * GK + kb + scol;
            const f32x4 x0 = *(const f32x4*)p, x1 = *(const f32x4*)(p + 4);
            const float* q = X + (size_t)(m0 + srow + 64) * GK + kb + scol;
            const f32x4 y0 = *(const f32x4*)q, y1 = *(const f32x4*)(q + 4);
#pragma unroll
            for (int c = 0; c < 4; ++c) {
                a0[c] = (bf16)x0[c]; a0[c + 4] = (bf16)x1[c];
                a1[c] = (bf16)y0[c]; a1[c + 4] = (bf16)y1[c];
            }
        }
        b0 = *(const bf16x8*)(Wt + (size_t)(n0 + srow) * GK + kb + scol);
        b1 = *(const bf16x8*)(Wt + (size_t)(n0 + srow + 64) * GK + kb + scol);
        __syncthreads();
        *(bf16x8*)(sA + srow * 32 + scol) = a0;
        *(bf16x8*)(sA + (srow + 64) * 32 + scol) = a1;
        *(bf16x8*)(sB + srow * 32 + scol) = b0;
        *(bf16x8*)(sB + (srow + 64) * 32 + scol) = b1;
        __syncthreads();
        bf16x8 af[4], bfr[4];
#pragma unroll
        for (int mi = 0; mi < 4; ++mi)
            af[mi] = *(const bf16x8*)(sA + (wm * 64 + mi * 16 + fr) * 32 + fq * 8);
#pragma unroll
        for (int ni = 0; ni < 4; ++ni)
            bfr[ni] = *(const bf16x8*)(sB + (wn * 64 + ni * 16 + fr) * 32 + fq * 8);
#pragma unroll
        for (int mi = 0; mi < 4; ++mi)
#pragma unroll
            for (int ni = 0; ni < 4; ++ni)
                acc[mi][ni] = __builtin_amdgcn_mfma_f32_16x16x32_bf16(
                    af[mi], bfr[ni], acc[mi][ni], 0, 0, 0);
    }
#pragma unroll
    for (int mi = 0; mi < 4; ++mi) {
#pragma unroll
        for (int ni = 0; ni < 4; ++ni) {
#pragma unroll
            for (int r = 0; r < 4; ++r) {
                const int m = m0 + wm * 64 + mi * 16 + fq * 4 + r;
                const int n = n0 + wn * 64 + ni * 16 + fr;
                const int bb = m >> 9, j = m & 511;
                const int ci = n >> 6, k = n & 63;
                U[(((size_t)(bb * NCAP + ci)) * IN_CAPS + j) * DCAP + k] =
                    (bf16)acc[mi][ni][r];
            }
        }
    }
}

// ---------------------------------------------------------------------------
// Kernel 4: routing pass v3 — 1024 threads per (b,cap) block.
// Each thread loads its 4 x bf16x8 (64 B) of the U slice ONCE and keeps them
// in registers (16 VGPRs) through squash; phase B runs from registers.
// Thread t: k-octet g=t&7 (k=g*8..g*8+7), j-group jp=t>>3 (j=it*128+jp).
//   mode 0: c = 1/16, write logits
//   mode 1: c = softmax(BL over capsule axis), write logits
//   mode 2: c = softmax(BL), write final output, no logits
// ---------------------------------------------------------------------------
__global__ __launch_bounds__(1024, 4) void k_route3(const bf16* __restrict__ U,
                                                    float* __restrict__ BL,
                                                    float* __restrict__ OutC,
                                                    int mode) {
    __shared__ float sc[IN_CAPS];   // 2 KiB: c[j]
    __shared__ float red[16][64];   // 4 KiB: per-wave partials per k
    __shared__ float sout[64];      // 256 B
    const int bi = blockIdx.x;      // b*16 + cap
    const int b = bi >> 4, cap = bi & 15;
    const int tid = threadIdx.x;
    const int lane = tid & 63, wave = tid >> 6;
    const int g = tid & 7, jp = tid >> 3; // jp = wave*8 + (lane>>3)
    const size_t ubase = (size_t)bi * IN_CAPS * DCAP;

    // --- load own U elements once (64 B/thread, perfectly coalesced) ---
    bf16x8 v[4];
#pragma unroll
    for (int it = 0; it < 4; ++it)
        v[it] = *(const bf16x8*)(U + ubase + (size_t)it * 8192 + tid * 8);

    // --- c coefficients ---
    if (tid < IN_CAPS) {
        if (mode == 0) {
            sc[tid] = 0.0625f;
        } else {
            const int j = tid;
            const float* p = BL + (size_t)b * NCAP * IN_CAPS + j;
            float vv[16], mx = -1e30f;
#pragma unroll
            for (int i = 0; i < 16; ++i) {
                vv[i] = p[(size_t)i * IN_CAPS];
                mx = fmaxf(mx, vv[i]);
            }
            float s = 0.f;
#pragma unroll
            for (int i = 0; i < 16; ++i) s += __expf(vv[i] - mx);
            sc[j] = __expf(vv[cap] - mx) / s;
        }
    }
    __syncthreads();

    // --- phase A: acc[c] = sum over own j's of c[j]*u[j][g*8+c] ---
    float acc[8] = {};
#pragma unroll
    for (int it = 0; it < 4; ++it) {
        const float cv = sc[it * 128 + jp];
#pragma unroll
        for (int c = 0; c < 8; ++c) acc[c] += cv * (float)v[it][c];
    }
    // intra-wave reduce over jp-bits (lane bits 3,4,5)
#pragma unroll
    for (int c = 0; c < 8; ++c) {
        acc[c] += __shfl_xor(acc[c], 8);
        acc[c] += __shfl_xor(acc[c], 16);
        acc[c] += __shfl_xor(acc[c], 32);
    }
    if (lane < 8) { // lane == g: holds wave-sum for k = lane*8 + c
#pragma unroll
        for (int c = 0; c < 8; ++c) red[wave][lane * 8 + c] = acc[c];
    }
    __syncthreads();

    // --- reduce 16 waves per k, squash ---
    if (tid < 64) {
        float s = 0.f;
#pragma unroll
        for (int w = 0; w < 16; ++w) s += red[w][tid];
        float ss = s * s;
#pragma unroll
        for (int off = 32; off >= 1; off >>= 1) ss += __shfl_xor(ss, off);
        const float val = s * rsqrtf(ss + 1e-7f);
        sout[tid] = val;
        if (mode == 2) OutC[(size_t)bi * DCAP + tid] = val;
    }
    if (mode == 2) return; // block-uniform
    __syncthreads();

    // --- phase B: logits from registers ---
    const f32x4 o0 = *(const f32x4*)(sout + g * 8);
    const f32x4 o1 = *(const f32x4*)(sout + g * 8 + 4);
#pragma unroll
    for (int it = 0; it < 4; ++it) {
        float p = o0[0] * (float)v[it][0] + o0[1] * (float)v[it][1] +
                  o0[2] * (float)v[it][2] + o0[3] * (float)v[it][3] +
                  o1[0] * (float)v[it][4] + o1[1] * (float)v[it][5] +
                  o1[2] * (float)v[it][6] + o1[3] * (float)v[it][7];
        p += __shfl_xor(p, 1); // reduce over g (lane bits 0..2)
        p += __shfl_xor(p, 2);
        p += __shfl_xor(p, 4);
        if (g == 0)
            BL[((size_t)b * NCAP + cap) * IN_CAPS + it * 128 + jp] = p;
    }
}

// ---------------------------------------------------------------------------
extern "C" void kernel_launch(void* const* d_in, const int* in_sizes, int n_in,
                              void* d_out, int out_size, void* d_ws, size_t ws_size,
                              hipStream_t stream) {
    const float* X = (const float*)d_in[0]; // [64][512][768] fp32
    const float* W = (const float*)d_in[1]; // [768][1024] fp32
    float* OutC = (float*)d_out;            // [64][16][64] fp32

    const size_t u_bytes = (size_t)BATCH * NCAP * IN_CAPS * DCAP * sizeof(bf16); // 64 MiB
    const size_t xb_bytes = (size_t)GM * GK * sizeof(bf16);                      // 48 MiB
    const size_t wt_bytes = (size_t)GN * GK * sizeof(bf16);                      // 1.5 MiB
    const size_t bl_bytes = (size_t)BATCH * NCAP * IN_CAPS * sizeof(float);      // 2 MiB
    char* ws = (char*)d_ws;

    const size_t need_big = u_bytes + xb_bytes + wt_bytes + bl_bytes;
    const size_t need_small = u_bytes + wt_bytes + bl_bytes;

    bf16* U = (bf16*)ws;
    bf16* Wt;
    float* BL;

    if (ws_size >= need_big) {
        bf16* Xb = (bf16*)(ws + u_bytes);
        Wt = (bf16*)(ws + u_bytes + xb_bytes);
        BL = (float*)(ws + u_bytes + xb_bytes + wt_bytes);
        k_convX<<<GM * GK / (256 * 8), 256, 0, stream>>>(X, Xb);
        k_transW<<<dim3(GK / 32, GN / 32), dim3(32, 8), 0, stream>>>(W, Wt);
        k_gemm_async<<<dim3(GM / 128, GN / 128), 256, 0, stream>>>(Xb, Wt, U);
    } else if (ws_size >= need_small) {
        Wt = (bf16*)(ws + u_bytes);
        BL = (float*)(ws + u_bytes + wt_bytes);
        k_transW<<<dim3(GK / 32, GN / 32), dim3(32, 8), 0, stream>>>(W, Wt);
        k_gemm_inline<<<dim3(GM / 128, GN / 128), 256, 0, stream>>>(X, Wt, U);
    } else {
        return;
    }

    // routing: 3 passes; U read once per pass, phase B from registers
    k_route3<<<BATCH * NCAP, 1024, 0, stream>>>(U, BL, OutC, 0);
    k_route3<<<BATCH * NCAP, 1024, 0, stream>>>(U, BL, OutC, 1);
    k_route3<<<BATCH * NCAP, 1024, 0, stream>>>(U, BL, OutC, 2);
}